// Round 3
// baseline (519.375 us; speedup 1.0000x reference)
//
#include <hip/hip_runtime.h>
#include <math.h>

// Dims (fixed by the problem)
#define Bv 4
#define Cv 256
#define Tv 64
#define Fv 256
#define Hv 8
#define HIDv 512
#define Mv 65536   // (B*T)*F rows
#define CTF (Cv * Tv * Fv)
#define TF (Tv * Fv)

typedef unsigned short u16;
typedef __attribute__((ext_vector_type(8))) short bfx8;
typedef __attribute__((ext_vector_type(4))) float f32x4;

__device__ __forceinline__ float bf2f(u16 u) {
  return __uint_as_float(((unsigned int)u) << 16);
}
__device__ __forceinline__ u16 f2bf(float f) {
  unsigned int x = __float_as_uint(f);
  unsigned int r = x + 0x7fffu + ((x >> 16) & 1u);
  return (u16)(r >> 16);
}
__device__ __forceinline__ unsigned int cvtpk(float a, float b) {
  unsigned int r;
  asm("v_cvt_pk_bf16_f32 %0, %1, %2" : "=v"(r) : "v"(a), "v"(b));
  return r;
}

// ---------------- one-shot weight transpose: fp32 [K][N] -> bf16 [N][K] ----------------
__launch_bounds__(256)
__global__ void transpose_w(const float* __restrict__ in, u16* __restrict__ out,
                            int K, int N) {
  __shared__ float t[32][33];
  const int n0 = blockIdx.x * 32, k0 = blockIdx.y * 32;
  const int c = threadIdx.x & 31, r = threadIdx.x >> 5;  // 32 cols x 8 rows
#pragma unroll
  for (int i = 0; i < 4; ++i)
    t[r + 8 * i][c] = in[(size_t)(k0 + r + 8 * i) * N + n0 + c];
  __syncthreads();
#pragma unroll
  for (int i = 0; i < 4; ++i)
    out[(size_t)(n0 + r + 8 * i) * K + k0 + c] = f2bf(t[c][r + 8 * i]);
}

// ---------------- LN1 fused with (B,C,T,F) -> (M, C) transpose; bf16 out ----------------
__launch_bounds__(256)
__global__ void ln1_kernel(const float* __restrict__ x, const float* __restrict__ g,
                           const float* __restrict__ bta, u16* __restrict__ xn) {
  __shared__ float tile[256][33];
  __shared__ float red1[8][32];
  __shared__ float red2[8][32];
  __shared__ float mu_s[32];
  __shared__ float rs_s[32];
  const int tid = threadIdx.x;
  const int blk = blockIdx.x;
  const int n = blk >> 3;           // 0..255 sequence index
  const int f0 = (blk & 7) << 5;    // 0,32,...,224
  const int bb = n >> 6, tt = n & 63;
  const float* xb = x + (size_t)bb * CTF + (size_t)tt * Fv;
  const int fl = tid & 31, c0 = tid >> 5;
#pragma unroll
  for (int i = 0; i < 32; ++i) {
    int c = i * 8 + c0;
    tile[c][fl] = xb[(size_t)c * TF + f0 + fl];
  }
  __syncthreads();
  const int col = tid & 31, part = tid >> 5;
  float s = 0.f, s2 = 0.f;
#pragma unroll
  for (int i = 0; i < 32; ++i) {
    float v = tile[part * 32 + i][col];
    s += v; s2 += v * v;
  }
  red1[part][col] = s; red2[part][col] = s2;
  __syncthreads();
  if (tid < 32) {
    float S1 = 0.f, S2 = 0.f;
#pragma unroll
    for (int p = 0; p < 8; ++p) { S1 += red1[p][tid]; S2 += red2[p][tid]; }
    float m = S1 * (1.f / 256.f);
    float var = S2 * (1.f / 256.f) - m * m;
    mu_s[tid] = m;
    rs_s[tid] = rsqrtf(var + 1e-5f);
  }
  __syncthreads();
  const float gv = g[tid], bv = bta[tid];
  u16* ob = xn + ((size_t)n * 256 + f0) * 256 + tid;
#pragma unroll
  for (int fl2 = 0; fl2 < 32; ++fl2) {
    ob[(size_t)fl2 * 256] = f2bf((tile[tid][fl2] - mu_s[fl2]) * rs_s[fl2] * gv + bv);
  }
}

// ---------------- MFMA GEMM: C[M,N] = A[M,K](bf16) @ Bt[N,K](bf16)^T + epilogue ----------
template <int K, int N, int EPI>
__launch_bounds__(256)
__global__ void gemm_mfma(const u16* __restrict__ A, const u16* __restrict__ Bt,
                          void* __restrict__ Cc, const float* __restrict__ aux0,
                          const u16* __restrict__ aux1) {
  constexpr int LDSTR = 88;  // u16 stride: 176 B, 16B-aligned, 2-way-free frag reads
  __shared__ u16 As[128 * LDSTR];
  __shared__ u16 Bs[128 * LDSTR];
  const int tid = threadIdx.x;
  const int lane = tid & 63, wid = tid >> 6;
  const int m0 = blockIdx.y * 128, n0 = blockIdx.x * 128;
  const int wm = (wid & 1) * 64, wn = (wid >> 1) * 64;
  const int lm = lane & 15, quad = lane >> 4;

  const int srow = tid >> 3, sch = tid & 7;

  f32x4 acc[4][4] = {};
  for (int k0 = 0; k0 < K; k0 += 64) {
    bfx8 ar[4], br[4];
#pragma unroll
    for (int i = 0; i < 4; ++i) {
      const int row = srow + i * 32;
      ar[i] = *(const bfx8*)(A + (size_t)(m0 + row) * K + k0 + sch * 8);
      br[i] = *(const bfx8*)(Bt + (size_t)(n0 + row) * K + k0 + sch * 8);
    }
    __syncthreads();
#pragma unroll
    for (int i = 0; i < 4; ++i) {
      const int row = srow + i * 32;
      *(bfx8*)&As[row * LDSTR + sch * 8] = ar[i];
      *(bfx8*)&Bs[row * LDSTR + sch * 8] = br[i];
    }
    __syncthreads();
#pragma unroll
    for (int s = 0; s < 2; ++s) {
      bfx8 af[4], bf[4];
#pragma unroll
      for (int t = 0; t < 4; ++t) {
        af[t] = *(const bfx8*)&As[(wm + t * 16 + lm) * LDSTR + s * 32 + quad * 8];
        bf[t] = *(const bfx8*)&Bs[(wn + t * 16 + lm) * LDSTR + s * 32 + quad * 8];
      }
#pragma unroll
      for (int tm = 0; tm < 4; ++tm)
#pragma unroll
        for (int tn = 0; tn < 4; ++tn)
          acc[tm][tn] = __builtin_amdgcn_mfma_f32_16x16x32_bf16(af[tm], bf[tn], acc[tm][tn], 0, 0, 0);
    }
  }

  const int row_l = quad * 4;
  const int nn = m0 >> 8;
  const int bb = nn >> 6, tt = nn & 63;
  const int srow_base = (m0 & 255) + wm;
  float bcol[4];
  if constexpr (EPI == 2 || EPI == 3) {
#pragma unroll
    for (int tn = 0; tn < 4; ++tn) bcol[tn] = aux0[n0 + wn + tn * 16 + lm];
  }
#pragma unroll
  for (int tm = 0; tm < 4; ++tm) {
    const int grow0 = m0 + wm + tm * 16 + row_l;
    const int sr0 = srow_base + tm * 16 + row_l;
#pragma unroll
    for (int tn = 0; tn < 4; ++tn) {
      const int gcol = n0 + wn + tn * 16 + lm;
      if constexpr (EPI == 0) {
#pragma unroll
        for (int r = 0; r < 4; ++r)
          ((u16*)Cc)[(size_t)(grow0 + r) * N + gcol] = f2bf(acc[tm][tn][r]);
      } else if constexpr (EPI == 1) {
        const float4 xv = *(const float4*)(aux0 + (size_t)bb * CTF + (size_t)gcol * TF + tt * Fv + sr0);
        const float xr[4] = {xv.x, xv.y, xv.z, xv.w};
#pragma unroll
        for (int r = 0; r < 4; ++r)
          ((u16*)Cc)[(size_t)(grow0 + r) * N + gcol] = f2bf(acc[tm][tn][r] + xr[r]);
      } else if constexpr (EPI == 2) {
#pragma unroll
        for (int r = 0; r < 4; ++r) {
          float v = acc[tm][tn][r] + bcol[tn];
          float y = 0.79788456080286536f * (v + 0.044715f * v * v * v);
          float th = 1.f - 2.f / (__expf(2.f * y) + 1.f);
          ((u16*)Cc)[(size_t)(grow0 + r) * N + gcol] = f2bf(0.5f * v * (1.f + th));
        }
      } else {  // EPI 3
        float4 o;
#pragma unroll
        for (int r = 0; r < 4; ++r) {
          float res = bf2f(aux1[(size_t)(grow0 + r) * 256 + gcol]);
          ((float*)&o)[r] = acc[tm][tn][r] + bcol[tn] + res;
        }
        *(float4*)((float*)Cc + (size_t)bb * CTF + (size_t)gcol * TF + tt * Fv + sr0) = o;
      }
    }
  }
}

// ---------------- MFMA flash attention: one block per (n,h), 8 waves ----------------
// Restructured for occupancy (was LDS-bound at 2 blocks/CU):
//  * Q conv+l2norm computed straight into B-frag registers (no Qs LDS, no barrier)
//  * P relayout (score C-frag -> PV A-frag) done in-register with
//    v_cvt_pk_bf16_f32 + v_permlane32/16_swap (no Pw LDS round-trip)
//  * K staged by waves 0-3, V by waves 4-7; double-buffered; 1 barrier/chunk
//  * V stored [d][key-octet^swz] so both b128 writes and reads are bank-uniform
__launch_bounds__(512, 4)
__global__ void attn_kernel(const u16* __restrict__ qkv, const float* __restrict__ dw,
                            const float* __restrict__ temp, u16* __restrict__ attn_out) {
  __shared__ u16 Kc[2][64 * 40];   // [key][ch] stride 40 u16 (80 B) — 5120 B each
  __shared__ u16 Vt[2][32 * 72];   // [d][key], key-octet XOR-swizzled — 4608 B each
  __shared__ float l_s[256];       // per-qrow softmax denominators
  const int tid = threadIdx.x;
  const int lane = tid & 63, w = tid >> 6;       // 8 waves, 32 qrows each
  const int l15 = lane & 15, quad = lane >> 4;
  const int n = blockIdx.x >> 3, h = blockIdx.x & 7;
  const int h32 = h * 32;
  const u16* base = qkv + (size_t)n * 256 * 768;
  const float th2 = temp[h] * 1.44269504089f;    // fold log2(e) into temperature

  // ---- Q: conv3 + l2norm directly into per-thread B-frags (qrow = w*32+ct*16+l15) ----
  bfx8 bq[2];
  {
    const int d0q = quad * 8;
    float wq[3][8];
#pragma unroll
    for (int j = 0; j < 8; ++j)
#pragma unroll
      for (int t = 0; t < 3; ++t) wq[t][j] = dw[(h32 + d0q + j) * 3 + t];
#pragma unroll
    for (int ct = 0; ct < 2; ++ct) {
      const int row = w * 32 + ct * 16 + l15;
      const u16* src = base + (size_t)row * 768 + h32 + d0q;
      float v[8];
      const bfx8 bm = *(const bfx8*)src;
#pragma unroll
      for (int j = 0; j < 8; ++j) v[j] = wq[1][j] * bf2f((u16)bm[j]);
      if (row > 0) {
        const bfx8 bp = *(const bfx8*)(src - 768);
#pragma unroll
        for (int j = 0; j < 8; ++j) v[j] += wq[0][j] * bf2f((u16)bp[j]);
      }
      if (row < 255) {
        const bfx8 bn = *(const bfx8*)(src + 768);
#pragma unroll
        for (int j = 0; j < 8; ++j) v[j] += wq[2][j] * bf2f((u16)bn[j]);
      }
      float ssq = 0.f;
#pragma unroll
      for (int j = 0; j < 8; ++j) ssq += v[j] * v[j];
      ssq += __shfl_xor(ssq, 16);
      ssq += __shfl_xor(ssq, 32);
      const float inv = 1.f / fmaxf(sqrtf(ssq), 1e-12f);
      union { unsigned int u[4]; bfx8 b; } qb;
#pragma unroll
      for (int m = 0; m < 4; ++m) qb.u[m] = cvtpk(v[2 * m] * inv, v[2 * m + 1] * inv);
      bq[ct] = qb.b;
    }
  }

  // ---- staging roles: waves 0-3 stage K (row x 8ch), waves 4-7 stage V (ch x 8 keys) ----
  const bool isK = tid < 256;
  const int sV = tid & 255;
  const int krow = sV >> 2, kd0 = (sV & 3) * 8;  // K-stager coords
  const int vd = sV & 31, vko = sV >> 5;         // V-stager coords (d, key-octet)
  float wu[24];                                  // conv taps (K: 24, V: 3)
  if (isK) {
#pragma unroll
    for (int j = 0; j < 8; ++j)
#pragma unroll
      for (int t = 0; t < 3; ++t) wu[t * 8 + j] = dw[(256 + h32 + kd0 + j) * 3 + t];
  } else {
#pragma unroll
    for (int t = 0; t < 3; ++t) wu[t] = dw[(512 + h32 + vd) * 3 + t];
  }

  bfx8 km = {}, kp = {}, kn = {};
  u16 xs[10];

  auto stage_load = [&](int c) {
    if (isK) {
      const int gr = c * 64 + krow;
      const u16* src = base + (size_t)gr * 768 + 256 + h32 + kd0;
      km = *(const bfx8*)src;
      kp = (gr > 0) ? *(const bfx8*)(src - 768) : bfx8{};
      kn = (gr < 255) ? *(const bfx8*)(src + 768) : bfx8{};
    } else {
      const int g0 = c * 64 + vko * 8;
      const u16* src = base + (size_t)g0 * 768 + 512 + h32 + vd;
#pragma unroll
      for (int k = 0; k < 10; ++k) {
        const int gr = g0 + k - 1;
        xs[k] = (gr >= 0 && gr < 256) ? src[(ptrdiff_t)(k - 1) * 768] : (u16)0;
      }
    }
  };
  auto stage_finish = [&](int b) {
    if (isK) {
      float v[8];
#pragma unroll
      for (int j = 0; j < 8; ++j)
        v[j] = wu[8 + j] * bf2f((u16)km[j]) + wu[j] * bf2f((u16)kp[j]) +
               wu[16 + j] * bf2f((u16)kn[j]);
      float ssq = 0.f;
#pragma unroll
      for (int j = 0; j < 8; ++j) ssq += v[j] * v[j];
      ssq += __shfl_xor(ssq, 1);
      ssq += __shfl_xor(ssq, 2);
      const float inv = 1.f / fmaxf(sqrtf(ssq), 1e-12f);
      union { unsigned int u[4]; bfx8 b; } kb;
#pragma unroll
      for (int m = 0; m < 4; ++m) kb.u[m] = cvtpk(v[2 * m] * inv, v[2 * m + 1] * inv);
      *(bfx8*)&Kc[b][krow * 40 + kd0] = kb.b;
    } else {
      float x[10];
#pragma unroll
      for (int k = 0; k < 10; ++k) x[k] = bf2f(xs[k]);
      union { unsigned int u[4]; bfx8 b; } ob;
#pragma unroll
      for (int m = 0; m < 4; ++m) {
        float a0 = wu[0] * x[2 * m] + wu[1] * x[2 * m + 1] + wu[2] * x[2 * m + 2];
        float a1 = wu[0] * x[2 * m + 1] + wu[1] * x[2 * m + 2] + wu[2] * x[2 * m + 3];
        ob.u[m] = cvtpk(a0, a1);
      }
      const int po = vko ^ ((vd >> 3) & 3);  // octet swizzle: conflict-free wr/rd
      *(bfx8*)&Vt[b][vd * 72 + po * 8] = ob.b;
    }
  };

  f32x4 acc[2][2] = {};
  float lsum[2] = {0.f, 0.f};
  const f32x4 zf = {0.f, 0.f, 0.f, 0.f};
  const int fo = (l15 >> 3) & 1;

  stage_load(0);
  stage_finish(0);
  __syncthreads();

  for (int c = 0; c < 4; ++c) {
    const int b = c & 1;
    if (c < 3) stage_load(c + 1);

    bfx8 af[4];
#pragma unroll
    for (int rt = 0; rt < 4; ++rt)
      af[rt] = *(const bfx8*)&Kc[b][(rt * 16 + l15) * 40 + quad * 8];
#pragma unroll
    for (int ct = 0; ct < 2; ++ct) {
      unsigned int pu[4], pv[4];
#pragma unroll
      for (int rt = 0; rt < 4; ++rt) {
        f32x4 sc = __builtin_amdgcn_mfma_f32_16x16x32_bf16(af[rt], bq[ct], zf, 0, 0, 0);
        float e0 = exp2f(sc[0] * th2), e1 = exp2f(sc[1] * th2);
        float e2 = exp2f(sc[2] * th2), e3 = exp2f(sc[3] * th2);
        lsum[ct] += (e0 + e1) + (e2 + e3);
        pu[rt] = cvtpk(e0, e1);
        pv[rt] = cvtpk(e2, e3);
      }
#pragma unroll
      for (int ks = 0; ks < 2; ++ks) {
        // cross-quad relayout: score frag (4 keys @ quad*4) -> PV A-frag (8 keys @ quad*8)
        // permlane swap convention: ret0 = arg0 with HIGH lanes <- arg1 LOW lanes (m214)
        auto su = __builtin_amdgcn_permlane32_swap(pu[2 * ks], pu[2 * ks + 1], false, false);
        auto tu = __builtin_amdgcn_permlane16_swap(su[0], su[1], false, false);
        auto sv = __builtin_amdgcn_permlane32_swap(pv[2 * ks], pv[2 * ks + 1], false, false);
        auto tv = __builtin_amdgcn_permlane16_swap(sv[0], sv[1], false, false);
        union { unsigned int u[4]; bfx8 b; } ap;
        ap.u[0] = tu[0]; ap.u[1] = tv[0]; ap.u[2] = tu[1]; ap.u[3] = tv[1];
        const bfx8 bv0 = *(const bfx8*)&Vt[b][l15 * 72 + (ks * 4 + (quad ^ fo)) * 8];
        const bfx8 bv1 = *(const bfx8*)&Vt[b][(16 + l15) * 72 + (ks * 4 + (quad ^ (2 | fo))) * 8];
        acc[ct][0] = __builtin_amdgcn_mfma_f32_16x16x32_bf16(ap.b, bv0, acc[ct][0], 0, 0, 0);
        acc[ct][1] = __builtin_amdgcn_mfma_f32_16x16x32_bf16(ap.b, bv1, acc[ct][1], 0, 0, 0);
      }
    }
    if (c < 3) stage_finish(b ^ 1);
    __syncthreads();
  }

  // ---- softmax denominators: reduce across quads (wave-local, no barrier needed) ----
#pragma unroll
  for (int ct = 0; ct < 2; ++ct) {
    float L = lsum[ct];
    L += __shfl_xor(L, 16);
    L += __shfl_xor(L, 32);
    if (quad == 0) l_s[w * 32 + ct * 16 + l15] = L;
  }
  // same-wave write->read; compiler inserts the lgkmcnt wait
#pragma unroll
  for (int ct = 0; ct < 2; ++ct) {
    const f32x4 l4 = *(const f32x4*)&l_s[w * 32 + ct * 16 + quad * 4];
    float rinv[4];
#pragma unroll
    for (int r = 0; r < 4; ++r) rinv[r] = 1.f / l4[r];
#pragma unroll
    for (int dh = 0; dh < 2; ++dh)
#pragma unroll
      for (int r = 0; r < 4; ++r) {
        const int qrow = w * 32 + ct * 16 + quad * 4 + r;
        attn_out[((size_t)n * 256 + qrow) * 256 + h32 + dh * 16 + l15] =
            f2bf(acc[ct][dh][r] * rinv[r]);
      }
  }
}

// ---------------- LN2: wave per row, bf16 in/out ----------------
__launch_bounds__(256)
__global__ void ln2_kernel(const u16* __restrict__ in, const float* __restrict__ g,
                           const float* __restrict__ bta, u16* __restrict__ out) {
  const int lane = threadIdx.x & 63;
  const size_t row = (size_t)blockIdx.x * 4 + (threadIdx.x >> 6);
  const ushort4 u = ((const ushort4*)(in + row * 256))[lane];
  const float vx = bf2f(u.x), vy = bf2f(u.y), vz = bf2f(u.z), vw = bf2f(u.w);
  float s = vx + vy + vz + vw;
  float s2 = vx * vx + vy * vy + vz * vz + vw * vw;
#pragma unroll
  for (int m = 32; m >= 1; m >>= 1) {
    s += __shfl_xor(s, m, 64);
    s2 += __shfl_xor(s2, m, 64);
  }
  const float mu = s * (1.f / 256.f);
  const float rs = rsqrtf(s2 * (1.f / 256.f) - mu * mu + 1e-5f);
  const float4 gv = ((const float4*)g)[lane];
  const float4 bv = ((const float4*)bta)[lane];
  ushort4 o;
  o.x = f2bf((vx - mu) * rs * gv.x + bv.x);
  o.y = f2bf((vy - mu) * rs * gv.y + bv.y);
  o.z = f2bf((vz - mu) * rs * gv.z + bv.z);
  o.w = f2bf((vw - mu) * rs * gv.w + bv.w);
  ((ushort4*)(out + row * 256))[lane] = o;
}

extern "C" void kernel_launch(void* const* d_in, const int* in_sizes, int n_in,
                              void* d_out, int out_size, void* d_ws, size_t ws_size,
                              hipStream_t stream) {
  const float* x     = (const float*)d_in[0];
  const float* n1g   = (const float*)d_in[1];
  const float* n1b   = (const float*)d_in[2];
  const float* Wqkv  = (const float*)d_in[3];
  const float* dw    = (const float*)d_in[4];
  const float* Wproj = (const float*)d_in[5];
  const float* temp  = (const float*)d_in[6];
  const float* n2g   = (const float*)d_in[7];
  const float* n2b   = (const float*)d_in[8];
  const float* W1    = (const float*)d_in[9];
  const float* b1    = (const float*)d_in[10];
  const float* W2    = (const float*)d_in[11];
  const float* b2    = (const float*)d_in[12];

  // workspace (bf16 intermediates, peak 128 MiB):
  //   [0,  32M): xn -> attn_out -> xn2 -> (after MLP1) W2t stash
  //   [32M,128M): qkv;  after attn: out1 at [32M,64M), h1 at [64M,128M)
  char* ws = (char*)d_ws;
  u16* xn       = (u16*)(ws);
  u16* qkv      = (u16*)(ws + (32ull << 20));
  u16* attn_out = xn;
  u16* out1     = (u16*)(ws + (32ull << 20));
  u16* xn2      = xn;
  u16* h1       = (u16*)(ws + (64ull << 20));
  u16* w2t      = xn;  // xn region is dead after MLP1 reads xn2

  // transposed-weight stash in d_out (fully overwritten by the final GEMM)
  char* ob = (char*)d_out;
  u16* wqkvt  = (u16*)(ob);                 // 384 KiB
  u16* wprojt = (u16*)(ob + (1ull << 20));  // 128 KiB
  u16* w1t    = (u16*)(ob + 1572864ull);    // 256 KiB (at 1.5 MiB)

  transpose_w<<<dim3(24, 8), 256, 0, stream>>>(Wqkv, wqkvt, 256, 768);
  transpose_w<<<dim3(8, 8), 256, 0, stream>>>(Wproj, wprojt, 256, 256);
  transpose_w<<<dim3(16, 8), 256, 0, stream>>>(W1, w1t, 256, 512);

  ln1_kernel<<<2048, 256, 0, stream>>>(x, n1g, n1b, xn);
  gemm_mfma<256, 768, 0><<<dim3(6, 512), 256, 0, stream>>>(xn, wqkvt, qkv, nullptr, nullptr);
  attn_kernel<<<2048, 512, 0, stream>>>(qkv, dw, temp, attn_out);
  gemm_mfma<256, 256, 1><<<dim3(2, 512), 256, 0, stream>>>(attn_out, wprojt, out1, x, nullptr);
  ln2_kernel<<<16384, 256, 0, stream>>>(out1, n2g, n2b, xn2);
  gemm_mfma<256, 512, 2><<<dim3(4, 512), 256, 0, stream>>>(xn2, W1 ? w1t : w1t, h1, b1, nullptr);
  transpose_w<<<dim3(8, 16), 256, 0, stream>>>(W2, w2t, 512, 256);
  gemm_mfma<512, 256, 3><<<dim3(2, 512), 256, 0, stream>>>(h1, w2t, d_out, b2, out1);
}

// Round 6
// 415.969 us; speedup vs baseline: 1.2486x; 1.2486x over previous
//
#include <hip/hip_runtime.h>
#include <math.h>

// Dims (fixed by the problem)
#define Bv 4
#define Cv 256
#define Tv 64
#define Fv 256
#define Hv 8
#define HIDv 512
#define Mv 65536   // (B*T)*F rows
#define CTF (Cv * Tv * Fv)
#define TF (Tv * Fv)

typedef unsigned short u16;
typedef __attribute__((ext_vector_type(8))) short bfx8;
typedef __attribute__((ext_vector_type(4))) float f32x4;

__device__ __forceinline__ float bf2f(u16 u) {
  return __uint_as_float(((unsigned int)u) << 16);
}
__device__ __forceinline__ u16 f2bf(float f) {
  unsigned int x = __float_as_uint(f);
  unsigned int r = x + 0x7fffu + ((x >> 16) & 1u);
  return (u16)(r >> 16);
}
__device__ __forceinline__ unsigned int cvtpk(float a, float b) {
  unsigned int r;
  asm("v_cvt_pk_bf16_f32 %0, %1, %2" : "=v"(r) : "v"(a), "v"(b));
  return r;
}

// ---------------- one-shot weight transpose: fp32 [K][N] -> bf16 [N][K] ----------------
__launch_bounds__(256)
__global__ void transpose_w(const float* __restrict__ in, u16* __restrict__ out,
                            int K, int N) {
  __shared__ float t[32][33];
  const int n0 = blockIdx.x * 32, k0 = blockIdx.y * 32;
  const int c = threadIdx.x & 31, r = threadIdx.x >> 5;  // 32 cols x 8 rows
#pragma unroll
  for (int i = 0; i < 4; ++i)
    t[r + 8 * i][c] = in[(size_t)(k0 + r + 8 * i) * N + n0 + c];
  __syncthreads();
#pragma unroll
  for (int i = 0; i < 4; ++i)
    out[(size_t)(n0 + r + 8 * i) * K + k0 + c] = f2bf(t[c][r + 8 * i]);
}

// ---------------- LN1 fused with (B,C,T,F) -> (M, C) transpose; bf16 out ----------------
__launch_bounds__(256)
__global__ void ln1_kernel(const float* __restrict__ x, const float* __restrict__ g,
                           const float* __restrict__ bta, u16* __restrict__ xn) {
  __shared__ float tile[256][33];
  __shared__ float red1[8][32];
  __shared__ float red2[8][32];
  __shared__ float mu_s[32];
  __shared__ float rs_s[32];
  const int tid = threadIdx.x;
  const int blk = blockIdx.x;
  const int n = blk >> 3;           // 0..255 sequence index
  const int f0 = (blk & 7) << 5;    // 0,32,...,224
  const int bb = n >> 6, tt = n & 63;
  const float* xb = x + (size_t)bb * CTF + (size_t)tt * Fv;
  const int fl = tid & 31, c0 = tid >> 5;
#pragma unroll
  for (int i = 0; i < 32; ++i) {
    int c = i * 8 + c0;
    tile[c][fl] = xb[(size_t)c * TF + f0 + fl];
  }
  __syncthreads();
  const int col = tid & 31, part = tid >> 5;
  float s = 0.f, s2 = 0.f;
#pragma unroll
  for (int i = 0; i < 32; ++i) {
    float v = tile[part * 32 + i][col];
    s += v; s2 += v * v;
  }
  red1[part][col] = s; red2[part][col] = s2;
  __syncthreads();
  if (tid < 32) {
    float S1 = 0.f, S2 = 0.f;
#pragma unroll
    for (int p = 0; p < 8; ++p) { S1 += red1[p][tid]; S2 += red2[p][tid]; }
    float m = S1 * (1.f / 256.f);
    float var = S2 * (1.f / 256.f) - m * m;
    mu_s[tid] = m;
    rs_s[tid] = rsqrtf(var + 1e-5f);
  }
  __syncthreads();
  const float gv = g[tid], bv = bta[tid];
  u16* ob = xn + ((size_t)n * 256 + f0) * 256 + tid;
#pragma unroll
  for (int fl2 = 0; fl2 < 32; ++fl2) {
    ob[(size_t)fl2 * 256] = f2bf((tile[tid][fl2] - mu_s[fl2]) * rs_s[fl2] * gv + bv);
  }
}

// ---------------- MFMA GEMM: C[M,N] = A[M,K](bf16) @ Bt[N,K](bf16)^T + epilogue ----------
template <int K, int N, int EPI>
__launch_bounds__(256)
__global__ void gemm_mfma(const u16* __restrict__ A, const u16* __restrict__ Bt,
                          void* __restrict__ Cc, const float* __restrict__ aux0,
                          const u16* __restrict__ aux1) {
  constexpr int LDSTR = 88;  // u16 stride: 176 B, 16B-aligned, 2-way-free frag reads
  __shared__ u16 As[128 * LDSTR];
  __shared__ u16 Bs[128 * LDSTR];
  const int tid = threadIdx.x;
  const int lane = tid & 63, wid = tid >> 6;
  const int m0 = blockIdx.y * 128, n0 = blockIdx.x * 128;
  const int wm = (wid & 1) * 64, wn = (wid >> 1) * 64;
  const int lm = lane & 15, quad = lane >> 4;

  const int srow = tid >> 3, sch = tid & 7;

  f32x4 acc[4][4] = {};
  for (int k0 = 0; k0 < K; k0 += 64) {
    bfx8 ar[4], br[4];
#pragma unroll
    for (int i = 0; i < 4; ++i) {
      const int row = srow + i * 32;
      ar[i] = *(const bfx8*)(A + (size_t)(m0 + row) * K + k0 + sch * 8);
      br[i] = *(const bfx8*)(Bt + (size_t)(n0 + row) * K + k0 + sch * 8);
    }
    __syncthreads();
#pragma unroll
    for (int i = 0; i < 4; ++i) {
      const int row = srow + i * 32;
      *(bfx8*)&As[row * LDSTR + sch * 8] = ar[i];
      *(bfx8*)&Bs[row * LDSTR + sch * 8] = br[i];
    }
    __syncthreads();
#pragma unroll
    for (int s = 0; s < 2; ++s) {
      bfx8 af[4], bf[4];
#pragma unroll
      for (int t = 0; t < 4; ++t) {
        af[t] = *(const bfx8*)&As[(wm + t * 16 + lm) * LDSTR + s * 32 + quad * 8];
        bf[t] = *(const bfx8*)&Bs[(wn + t * 16 + lm) * LDSTR + s * 32 + quad * 8];
      }
#pragma unroll
      for (int tm = 0; tm < 4; ++tm)
#pragma unroll
        for (int tn = 0; tn < 4; ++tn)
          acc[tm][tn] = __builtin_amdgcn_mfma_f32_16x16x32_bf16(af[tm], bf[tn], acc[tm][tn], 0, 0, 0);
    }
  }

  const int row_l = quad * 4;
  const int nn = m0 >> 8;
  const int bb = nn >> 6, tt = nn & 63;
  const int srow_base = (m0 & 255) + wm;
  float bcol[4];
  if constexpr (EPI == 2 || EPI == 3) {
#pragma unroll
    for (int tn = 0; tn < 4; ++tn) bcol[tn] = aux0[n0 + wn + tn * 16 + lm];
  }
#pragma unroll
  for (int tm = 0; tm < 4; ++tm) {
    const int grow0 = m0 + wm + tm * 16 + row_l;
    const int sr0 = srow_base + tm * 16 + row_l;
#pragma unroll
    for (int tn = 0; tn < 4; ++tn) {
      const int gcol = n0 + wn + tn * 16 + lm;
      if constexpr (EPI == 0) {
#pragma unroll
        for (int r = 0; r < 4; ++r)
          ((u16*)Cc)[(size_t)(grow0 + r) * N + gcol] = f2bf(acc[tm][tn][r]);
      } else if constexpr (EPI == 1) {
        const float4 xv = *(const float4*)(aux0 + (size_t)bb * CTF + (size_t)gcol * TF + tt * Fv + sr0);
        const float xr[4] = {xv.x, xv.y, xv.z, xv.w};
#pragma unroll
        for (int r = 0; r < 4; ++r)
          ((u16*)Cc)[(size_t)(grow0 + r) * N + gcol] = f2bf(acc[tm][tn][r] + xr[r]);
      } else if constexpr (EPI == 2) {
#pragma unroll
        for (int r = 0; r < 4; ++r) {
          float v = acc[tm][tn][r] + bcol[tn];
          float y = 0.79788456080286536f * (v + 0.044715f * v * v * v);
          float th = 1.f - 2.f / (__expf(2.f * y) + 1.f);
          ((u16*)Cc)[(size_t)(grow0 + r) * N + gcol] = f2bf(0.5f * v * (1.f + th));
        }
      } else {  // EPI 3
        float4 o;
#pragma unroll
        for (int r = 0; r < 4; ++r) {
          float res = bf2f(aux1[(size_t)(grow0 + r) * 256 + gcol]);
          ((float*)&o)[r] = acc[tm][tn][r] + bcol[tn] + res;
        }
        *(float4*)((float*)Cc + (size_t)bb * CTF + (size_t)gcol * TF + tt * Fv + sr0) = o;
      }
    }
  }
}

// ---------------- MFMA flash attention: one block per (n,h), 8 waves ----------------
// Same verified structure as round 3; ONLY change: __launch_bounds__(512) without
// the min-waves arg. (512,4) made the unified VGPR+AGPR budget 128/wave -> 64
// arch VGPRs -> ~50 regs of per-thread scratch spill (WRITE_SIZE 433 MB).
__launch_bounds__(512)
__global__ void attn_kernel(const u16* __restrict__ qkv, const float* __restrict__ dw,
                            const float* __restrict__ temp, u16* __restrict__ attn_out) {
  __shared__ u16 Kc[2][64 * 40];   // [key][ch] stride 40 u16 (80 B) — 5120 B each
  __shared__ u16 Vt[2][32 * 72];   // [d][key], key-octet XOR-swizzled — 4608 B each
  __shared__ float l_s[256];       // per-qrow softmax denominators
  const int tid = threadIdx.x;
  const int lane = tid & 63, w = tid >> 6;       // 8 waves, 32 qrows each
  const int l15 = lane & 15, quad = lane >> 4;
  const int n = blockIdx.x >> 3, h = blockIdx.x & 7;
  const int h32 = h * 32;
  const u16* base = qkv + (size_t)n * 256 * 768;
  const float th2 = temp[h] * 1.44269504089f;    // fold log2(e) into temperature

  // ---- Q: conv3 + l2norm directly into per-thread B-frags (qrow = w*32+ct*16+l15) ----
  bfx8 bq[2];
  {
    const int d0q = quad * 8;
    float wq[3][8];
#pragma unroll
    for (int j = 0; j < 8; ++j)
#pragma unroll
      for (int t = 0; t < 3; ++t) wq[t][j] = dw[(h32 + d0q + j) * 3 + t];
#pragma unroll
    for (int ct = 0; ct < 2; ++ct) {
      const int row = w * 32 + ct * 16 + l15;
      const u16* src = base + (size_t)row * 768 + h32 + d0q;
      float v[8];
      const bfx8 bm = *(const bfx8*)src;
#pragma unroll
      for (int j = 0; j < 8; ++j) v[j] = wq[1][j] * bf2f((u16)bm[j]);
      if (row > 0) {
        const bfx8 bp = *(const bfx8*)(src - 768);
#pragma unroll
        for (int j = 0; j < 8; ++j) v[j] += wq[0][j] * bf2f((u16)bp[j]);
      }
      if (row < 255) {
        const bfx8 bn = *(const bfx8*)(src + 768);
#pragma unroll
        for (int j = 0; j < 8; ++j) v[j] += wq[2][j] * bf2f((u16)bn[j]);
      }
      float ssq = 0.f;
#pragma unroll
      for (int j = 0; j < 8; ++j) ssq += v[j] * v[j];
      ssq += __shfl_xor(ssq, 16);
      ssq += __shfl_xor(ssq, 32);
      const float inv = 1.f / fmaxf(sqrtf(ssq), 1e-12f);
      union { unsigned int u[4]; bfx8 b; } qb;
#pragma unroll
      for (int m = 0; m < 4; ++m) qb.u[m] = cvtpk(v[2 * m] * inv, v[2 * m + 1] * inv);
      bq[ct] = qb.b;
    }
  }

  // ---- staging roles: waves 0-3 stage K (row x 8ch), waves 4-7 stage V (ch x 8 keys) ----
  const bool isK = tid < 256;
  const int sV = tid & 255;
  const int krow = sV >> 2, kd0 = (sV & 3) * 8;  // K-stager coords
  const int vd = sV & 31, vko = sV >> 5;         // V-stager coords (d, key-octet)
  float wu[24];                                  // conv taps (K: 24, V: 3)
  if (isK) {
#pragma unroll
    for (int j = 0; j < 8; ++j)
#pragma unroll
      for (int t = 0; t < 3; ++t) wu[t * 8 + j] = dw[(256 + h32 + kd0 + j) * 3 + t];
  } else {
#pragma unroll
    for (int t = 0; t < 3; ++t) wu[t] = dw[(512 + h32 + vd) * 3 + t];
  }

  bfx8 km = {}, kp = {}, kn = {};
  u16 xs[10];

  auto stage_load = [&](int c) {
    if (isK) {
      const int gr = c * 64 + krow;
      const u16* src = base + (size_t)gr * 768 + 256 + h32 + kd0;
      km = *(const bfx8*)src;
      kp = (gr > 0) ? *(const bfx8*)(src - 768) : bfx8{};
      kn = (gr < 255) ? *(const bfx8*)(src + 768) : bfx8{};
    } else {
      const int g0 = c * 64 + vko * 8;
      const u16* src = base + (size_t)g0 * 768 + 512 + h32 + vd;
#pragma unroll
      for (int k = 0; k < 10; ++k) {
        const int gr = g0 + k - 1;
        xs[k] = (gr >= 0 && gr < 256) ? src[(ptrdiff_t)(k - 1) * 768] : (u16)0;
      }
    }
  };
  auto stage_finish = [&](int b) {
    if (isK) {
      float v[8];
#pragma unroll
      for (int j = 0; j < 8; ++j)
        v[j] = wu[8 + j] * bf2f((u16)km[j]) + wu[j] * bf2f((u16)kp[j]) +
               wu[16 + j] * bf2f((u16)kn[j]);
      float ssq = 0.f;
#pragma unroll
      for (int j = 0; j < 8; ++j) ssq += v[j] * v[j];
      ssq += __shfl_xor(ssq, 1);
      ssq += __shfl_xor(ssq, 2);
      const float inv = 1.f / fmaxf(sqrtf(ssq), 1e-12f);
      union { unsigned int u[4]; bfx8 b; } kb;
#pragma unroll
      for (int m = 0; m < 4; ++m) kb.u[m] = cvtpk(v[2 * m] * inv, v[2 * m + 1] * inv);
      *(bfx8*)&Kc[b][krow * 40 + kd0] = kb.b;
    } else {
      float x[10];
#pragma unroll
      for (int k = 0; k < 10; ++k) x[k] = bf2f(xs[k]);
      union { unsigned int u[4]; bfx8 b; } ob;
#pragma unroll
      for (int m = 0; m < 4; ++m) {
        float a0 = wu[0] * x[2 * m] + wu[1] * x[2 * m + 1] + wu[2] * x[2 * m + 2];
        float a1 = wu[0] * x[2 * m + 1] + wu[1] * x[2 * m + 2] + wu[2] * x[2 * m + 3];
        ob.u[m] = cvtpk(a0, a1);
      }
      const int po = vko ^ ((vd >> 3) & 3);  // octet swizzle: conflict-free wr/rd
      *(bfx8*)&Vt[b][vd * 72 + po * 8] = ob.b;
    }
  };

  f32x4 acc[2][2] = {};
  float lsum[2] = {0.f, 0.f};
  const f32x4 zf = {0.f, 0.f, 0.f, 0.f};
  const int fo = (l15 >> 3) & 1;

  stage_load(0);
  stage_finish(0);
  __syncthreads();

  for (int c = 0; c < 4; ++c) {
    const int b = c & 1;
    if (c < 3) stage_load(c + 1);

    bfx8 af[4];
#pragma unroll
    for (int rt = 0; rt < 4; ++rt)
      af[rt] = *(const bfx8*)&Kc[b][(rt * 16 + l15) * 40 + quad * 8];
#pragma unroll
    for (int ct = 0; ct < 2; ++ct) {
      unsigned int pu[4], pv[4];
#pragma unroll
      for (int rt = 0; rt < 4; ++rt) {
        f32x4 sc = __builtin_amdgcn_mfma_f32_16x16x32_bf16(af[rt], bq[ct], zf, 0, 0, 0);
        float e0 = exp2f(sc[0] * th2), e1 = exp2f(sc[1] * th2);
        float e2 = exp2f(sc[2] * th2), e3 = exp2f(sc[3] * th2);
        lsum[ct] += (e0 + e1) + (e2 + e3);
        pu[rt] = cvtpk(e0, e1);
        pv[rt] = cvtpk(e2, e3);
      }
#pragma unroll
      for (int ks = 0; ks < 2; ++ks) {
        // cross-quad relayout: score frag (4 keys @ quad*4) -> PV A-frag (8 keys @ quad*8)
        auto su = __builtin_amdgcn_permlane32_swap(pu[2 * ks], pu[2 * ks + 1], false, false);
        auto tu = __builtin_amdgcn_permlane16_swap(su[0], su[1], false, false);
        auto sv = __builtin_amdgcn_permlane32_swap(pv[2 * ks], pv[2 * ks + 1], false, false);
        auto tv = __builtin_amdgcn_permlane16_swap(sv[0], sv[1], false, false);
        union { unsigned int u[4]; bfx8 b; } ap;
        ap.u[0] = tu[0]; ap.u[1] = tv[0]; ap.u[2] = tu[1]; ap.u[3] = tv[1];
        const bfx8 bv0 = *(const bfx8*)&Vt[b][l15 * 72 + (ks * 4 + (quad ^ fo)) * 8];
        const bfx8 bv1 = *(const bfx8*)&Vt[b][(16 + l15) * 72 + (ks * 4 + (quad ^ (2 | fo))) * 8];
        acc[ct][0] = __builtin_amdgcn_mfma_f32_16x16x32_bf16(ap.b, bv0, acc[ct][0], 0, 0, 0);
        acc[ct][1] = __builtin_amdgcn_mfma_f32_16x16x32_bf16(ap.b, bv1, acc[ct][1], 0, 0, 0);
      }
    }
    if (c < 3) stage_finish(b ^ 1);
    __syncthreads();
  }

  // ---- softmax denominators: reduce across quads (wave-local, no barrier needed) ----
#pragma unroll
  for (int ct = 0; ct < 2; ++ct) {
    float L = lsum[ct];
    L += __shfl_xor(L, 16);
    L += __shfl_xor(L, 32);
    if (quad == 0) l_s[w * 32 + ct * 16 + l15] = L;
  }
  // same-wave write->read; compiler inserts the lgkmcnt wait
#pragma unroll
  for (int ct = 0; ct < 2; ++ct) {
    const f32x4 l4 = *(const f32x4*)&l_s[w * 32 + ct * 16 + quad * 4];
    float rinv[4];
#pragma unroll
    for (int r = 0; r < 4; ++r) rinv[r] = 1.f / l4[r];
#pragma unroll
    for (int dh = 0; dh < 2; ++dh)
#pragma unroll
      for (int r = 0; r < 4; ++r) {
        const int qrow = w * 32 + ct * 16 + quad * 4 + r;
        attn_out[((size_t)n * 256 + qrow) * 256 + h32 + dh * 16 + l15] =
            f2bf(acc[ct][dh][r] * rinv[r]);
      }
  }
}

// ---------------- LN2: wave per row, bf16 in/out ----------------
__launch_bounds__(256)
__global__ void ln2_kernel(const u16* __restrict__ in, const float* __restrict__ g,
                           const float* __restrict__ bta, u16* __restrict__ out) {
  const int lane = threadIdx.x & 63;
  const size_t row = (size_t)blockIdx.x * 4 + (threadIdx.x >> 6);
  const ushort4 u = ((const ushort4*)(in + row * 256))[lane];
  const float vx = bf2f(u.x), vy = bf2f(u.y), vz = bf2f(u.z), vw = bf2f(u.w);
  float s = vx + vy + vz + vw;
  float s2 = vx * vx + vy * vy + vz * vz + vw * vw;
#pragma unroll
  for (int m = 32; m >= 1; m >>= 1) {
    s += __shfl_xor(s, m, 64);
    s2 += __shfl_xor(s2, m, 64);
  }
  const float mu = s * (1.f / 256.f);
  const float rs = rsqrtf(s2 * (1.f / 256.f) - mu * mu + 1e-5f);
  const float4 gv = ((const float4*)g)[lane];
  const float4 bv = ((const float4*)bta)[lane];
  ushort4 o;
  o.x = f2bf((vx - mu) * rs * gv.x + bv.x);
  o.y = f2bf((vy - mu) * rs * gv.y + bv.y);
  o.z = f2bf((vz - mu) * rs * gv.z + bv.z);
  o.w = f2bf((vw - mu) * rs * gv.w + bv.w);
  ((ushort4*)(out + row * 256))[lane] = o;
}

extern "C" void kernel_launch(void* const* d_in, const int* in_sizes, int n_in,
                              void* d_out, int out_size, void* d_ws, size_t ws_size,
                              hipStream_t stream) {
  const float* x     = (const float*)d_in[0];
  const float* n1g   = (const float*)d_in[1];
  const float* n1b   = (const float*)d_in[2];
  const float* Wqkv  = (const float*)d_in[3];
  const float* dw    = (const float*)d_in[4];
  const float* Wproj = (const float*)d_in[5];
  const float* temp  = (const float*)d_in[6];
  const float* n2g   = (const float*)d_in[7];
  const float* n2b   = (const float*)d_in[8];
  const float* W1    = (const float*)d_in[9];
  const float* b1    = (const float*)d_in[10];
  const float* W2    = (const float*)d_in[11];
  const float* b2    = (const float*)d_in[12];

  // workspace (bf16 intermediates, peak 128 MiB):
  //   [0,  32M): xn -> attn_out -> xn2 -> (after MLP1) W2t stash
  //   [32M,128M): qkv;  after attn: out1 at [32M,64M), h1 at [64M,128M)
  char* ws = (char*)d_ws;
  u16* xn       = (u16*)(ws);
  u16* qkv      = (u16*)(ws + (32ull << 20));
  u16* attn_out = xn;
  u16* out1     = (u16*)(ws + (32ull << 20));
  u16* xn2      = xn;
  u16* h1       = (u16*)(ws + (64ull << 20));
  u16* w2t      = xn;  // xn region is dead after MLP1 reads xn2

  // transposed-weight stash in d_out (fully overwritten by the final GEMM)
  char* ob = (char*)d_out;
  u16* wqkvt  = (u16*)(ob);                 // 384 KiB
  u16* wprojt = (u16*)(ob + (1ull << 20));  // 128 KiB
  u16* w1t    = (u16*)(ob + 1572864ull);    // 256 KiB (at 1.5 MiB)

  transpose_w<<<dim3(24, 8), 256, 0, stream>>>(Wqkv, wqkvt, 256, 768);
  transpose_w<<<dim3(8, 8), 256, 0, stream>>>(Wproj, wprojt, 256, 256);
  transpose_w<<<dim3(16, 8), 256, 0, stream>>>(W1, w1t, 256, 512);

  ln1_kernel<<<2048, 256, 0, stream>>>(x, n1g, n1b, xn);
  gemm_mfma<256, 768, 0><<<dim3(6, 512), 256, 0, stream>>>(xn, wqkvt, qkv, nullptr, nullptr);
  attn_kernel<<<2048, 512, 0, stream>>>(qkv, dw, temp, attn_out);
  gemm_mfma<256, 256, 1><<<dim3(2, 512), 256, 0, stream>>>(attn_out, wprojt, out1, x, nullptr);
  ln2_kernel<<<16384, 256, 0, stream>>>(out1, n2g, n2b, xn2);
  gemm_mfma<256, 512, 2><<<dim3(4, 512), 256, 0, stream>>>(xn2, W1 ? w1t : w1t, h1, b1, nullptr);
  transpose_w<<<dim3(8, 16), 256, 0, stream>>>(W2, w2t, 512, 256);
  gemm_mfma<512, 256, 3><<<dim3(2, 512), 256, 0, stream>>>(h1, w2t, d_out, b2, out1);
}

// Round 7
// 396.801 us; speedup vs baseline: 1.3089x; 1.0483x over previous
//
#include <hip/hip_runtime.h>
#include <math.h>

// Dims (fixed by the problem)
#define Bv 4
#define Cv 256
#define Tv 64
#define Fv 256
#define Hv 8
#define HIDv 512
#define Mv 65536   // (B*T)*F rows
#define CTF (Cv * Tv * Fv)
#define TF (Tv * Fv)

typedef unsigned short u16;
typedef __attribute__((ext_vector_type(8))) short bfx8;
typedef __attribute__((ext_vector_type(4))) float f32x4;

__device__ __forceinline__ float bf2f(u16 u) {
  return __uint_as_float(((unsigned int)u) << 16);
}
__device__ __forceinline__ u16 f2bf(float f) {
  unsigned int x = __float_as_uint(f);
  unsigned int r = x + 0x7fffu + ((x >> 16) & 1u);
  return (u16)(r >> 16);
}
__device__ __forceinline__ unsigned int cvtpk(float a, float b) {
  unsigned int r;
  asm("v_cvt_pk_bf16_f32 %0, %1, %2" : "=v"(r) : "v"(a), "v"(b));
  return r;
}

// ---------------- one-shot weight transpose: fp32 [K][N] -> bf16 [N][K] ----------------
__launch_bounds__(256)
__global__ void transpose_w(const float* __restrict__ in, u16* __restrict__ out,
                            int K, int N) {
  __shared__ float t[32][33];
  const int n0 = blockIdx.x * 32, k0 = blockIdx.y * 32;
  const int c = threadIdx.x & 31, r = threadIdx.x >> 5;  // 32 cols x 8 rows
#pragma unroll
  for (int i = 0; i < 4; ++i)
    t[r + 8 * i][c] = in[(size_t)(k0 + r + 8 * i) * N + n0 + c];
  __syncthreads();
#pragma unroll
  for (int i = 0; i < 4; ++i)
    out[(size_t)(n0 + r + 8 * i) * K + k0 + c] = f2bf(t[c][r + 8 * i]);
}

// ---------------- LN1 fused with (B,C,T,F) -> (M, C) transpose; bf16 out ----------------
__launch_bounds__(256)
__global__ void ln1_kernel(const float* __restrict__ x, const float* __restrict__ g,
                           const float* __restrict__ bta, u16* __restrict__ xn) {
  __shared__ float tile[256][33];
  __shared__ float red1[8][32];
  __shared__ float red2[8][32];
  __shared__ float mu_s[32];
  __shared__ float rs_s[32];
  const int tid = threadIdx.x;
  const int blk = blockIdx.x;
  const int n = blk >> 3;           // 0..255 sequence index
  const int f0 = (blk & 7) << 5;    // 0,32,...,224
  const int bb = n >> 6, tt = n & 63;
  const float* xb = x + (size_t)bb * CTF + (size_t)tt * Fv;
  const int fl = tid & 31, c0 = tid >> 5;
#pragma unroll
  for (int i = 0; i < 32; ++i) {
    int c = i * 8 + c0;
    tile[c][fl] = xb[(size_t)c * TF + f0 + fl];
  }
  __syncthreads();
  const int col = tid & 31, part = tid >> 5;
  float s = 0.f, s2 = 0.f;
#pragma unroll
  for (int i = 0; i < 32; ++i) {
    float v = tile[part * 32 + i][col];
    s += v; s2 += v * v;
  }
  red1[part][col] = s; red2[part][col] = s2;
  __syncthreads();
  if (tid < 32) {
    float S1 = 0.f, S2 = 0.f;
#pragma unroll
    for (int p = 0; p < 8; ++p) { S1 += red1[p][tid]; S2 += red2[p][tid]; }
    float m = S1 * (1.f / 256.f);
    float var = S2 * (1.f / 256.f) - m * m;
    mu_s[tid] = m;
    rs_s[tid] = rsqrtf(var + 1e-5f);
  }
  __syncthreads();
  const float gv = g[tid], bv = bta[tid];
  u16* ob = xn + ((size_t)n * 256 + f0) * 256 + tid;
#pragma unroll
  for (int fl2 = 0; fl2 < 32; ++fl2) {
    ob[(size_t)fl2 * 256] = f2bf((tile[tid][fl2] - mu_s[fl2]) * rs_s[fl2] * gv + bv);
  }
}

// ---------------- MFMA GEMM: C[M,N] = A[M,K](bf16) @ Bt[N,K](bf16)^T + epilogue ----------
// Round-7: T14 issue-early/write-late pipeline (next tile's global loads issued
// BEFORE compute so HBM latency hides under the 32-MFMA phase) + bijective
// XCD-chunk swizzle (nwg % 8 == 0 for all four launches).
template <int K, int N, int EPI>
__launch_bounds__(256)
__global__ void gemm_mfma(const u16* __restrict__ A, const u16* __restrict__ Bt,
                          void* __restrict__ Cc, const float* __restrict__ aux0,
                          const u16* __restrict__ aux1) {
  constexpr int LDSTR = 88;  // u16 stride: 176 B, 16B-aligned, 2-way-free frag reads
  constexpr int GX = N / 128;
  __shared__ u16 As[128 * LDSTR];
  __shared__ u16 Bs[128 * LDSTR];
  const int tid = threadIdx.x;
  const int lane = tid & 63, wid = tid >> 6;
  // XCD-aware swizzle: XCD k (blocks id%8==k) gets a contiguous logical chunk
  {
  }
  const int nwg = GX * (Mv / 128) / ((Mv / 128) / gridDim.y);  // = gridDim.x*gridDim.y
  int id = blockIdx.y * GX + blockIdx.x;
  const int qch = (GX * gridDim.y) >> 3;
  id = (id & 7) * qch + (id >> 3);
  const int m0 = (id / GX) * 128, n0 = (id % GX) * 128;
  (void)nwg;
  const int wm = (wid & 1) * 64, wn = (wid >> 1) * 64;
  const int lm = lane & 15, quad = lane >> 4;

  const int srow = tid >> 3, sch = tid & 7;

  f32x4 acc[4][4] = {};
  bfx8 ar[4], br[4];
  auto gload = [&](int k0) {
#pragma unroll
    for (int i = 0; i < 4; ++i) {
      const int row = srow + i * 32;
      ar[i] = *(const bfx8*)(A + (size_t)(m0 + row) * K + k0 + sch * 8);
      br[i] = *(const bfx8*)(Bt + (size_t)(n0 + row) * K + k0 + sch * 8);
    }
  };
  gload(0);
  for (int k0 = 0; k0 < K; k0 += 64) {
    __syncthreads();  // previous compute done reading LDS
#pragma unroll
    for (int i = 0; i < 4; ++i) {
      const int row = srow + i * 32;
      *(bfx8*)&As[row * LDSTR + sch * 8] = ar[i];
      *(bfx8*)&Bs[row * LDSTR + sch * 8] = br[i];
    }
    __syncthreads();
    if (k0 + 64 < K) gload(k0 + 64);  // in flight during the MFMA phase below
#pragma unroll
    for (int s = 0; s < 2; ++s) {
      bfx8 af[4], bf[4];
#pragma unroll
      for (int t = 0; t < 4; ++t) {
        af[t] = *(const bfx8*)&As[(wm + t * 16 + lm) * LDSTR + s * 32 + quad * 8];
        bf[t] = *(const bfx8*)&Bs[(wn + t * 16 + lm) * LDSTR + s * 32 + quad * 8];
      }
#pragma unroll
      for (int tm = 0; tm < 4; ++tm)
#pragma unroll
        for (int tn = 0; tn < 4; ++tn)
          acc[tm][tn] = __builtin_amdgcn_mfma_f32_16x16x32_bf16(af[tm], bf[tn], acc[tm][tn], 0, 0, 0);
    }
  }

  const int row_l = quad * 4;
  const int nn = m0 >> 8;
  const int bb = nn >> 6, tt = nn & 63;
  const int srow_base = (m0 & 255) + wm;
  float bcol[4];
  if constexpr (EPI == 2 || EPI == 3) {
#pragma unroll
    for (int tn = 0; tn < 4; ++tn) bcol[tn] = aux0[n0 + wn + tn * 16 + lm];
  }
#pragma unroll
  for (int tm = 0; tm < 4; ++tm) {
    const int grow0 = m0 + wm + tm * 16 + row_l;
    const int sr0 = srow_base + tm * 16 + row_l;
#pragma unroll
    for (int tn = 0; tn < 4; ++tn) {
      const int gcol = n0 + wn + tn * 16 + lm;
      if constexpr (EPI == 0) {
#pragma unroll
        for (int r = 0; r < 4; ++r)
          ((u16*)Cc)[(size_t)(grow0 + r) * N + gcol] = f2bf(acc[tm][tn][r]);
      } else if constexpr (EPI == 1) {
        const float4 xv = *(const float4*)(aux0 + (size_t)bb * CTF + (size_t)gcol * TF + tt * Fv + sr0);
        const float xr[4] = {xv.x, xv.y, xv.z, xv.w};
#pragma unroll
        for (int r = 0; r < 4; ++r)
          ((u16*)Cc)[(size_t)(grow0 + r) * N + gcol] = f2bf(acc[tm][tn][r] + xr[r]);
      } else if constexpr (EPI == 2) {
#pragma unroll
        for (int r = 0; r < 4; ++r) {
          float v = acc[tm][tn][r] + bcol[tn];
          float y = 0.79788456080286536f * (v + 0.044715f * v * v * v);
          float th = 1.f - 2.f / (__expf(2.f * y) + 1.f);
          ((u16*)Cc)[(size_t)(grow0 + r) * N + gcol] = f2bf(0.5f * v * (1.f + th));
        }
      } else {  // EPI 3
        float4 o;
#pragma unroll
        for (int r = 0; r < 4; ++r) {
          float res = bf2f(aux1[(size_t)(grow0 + r) * 256 + gcol]);
          ((float*)&o)[r] = acc[tm][tn][r] + bcol[tn] + res;
        }
        *(float4*)((float*)Cc + (size_t)bb * CTF + (size_t)gcol * TF + tt * Fv + sr0) = o;
      }
    }
  }
}

// ---------------- MFMA flash attention: one block per (n,h), 8 waves ----------------
// Verified structure (round 6: 100.7 us, no spill at VGPR=108).
__launch_bounds__(512)
__global__ void attn_kernel(const u16* __restrict__ qkv, const float* __restrict__ dw,
                            const float* __restrict__ temp, u16* __restrict__ attn_out) {
  __shared__ u16 Kc[2][64 * 40];   // [key][ch] stride 40 u16 (80 B) — 5120 B each
  __shared__ u16 Vt[2][32 * 72];   // [d][key], key-octet XOR-swizzled — 4608 B each
  __shared__ float l_s[256];       // per-qrow softmax denominators
  const int tid = threadIdx.x;
  const int lane = tid & 63, w = tid >> 6;       // 8 waves, 32 qrows each
  const int l15 = lane & 15, quad = lane >> 4;
  const int n = blockIdx.x >> 3, h = blockIdx.x & 7;
  const int h32 = h * 32;
  const u16* base = qkv + (size_t)n * 256 * 768;
  const float th2 = temp[h] * 1.44269504089f;    // fold log2(e) into temperature

  // ---- Q: conv3 + l2norm directly into per-thread B-frags (qrow = w*32+ct*16+l15) ----
  bfx8 bq[2];
  {
    const int d0q = quad * 8;
    float wq[3][8];
#pragma unroll
    for (int j = 0; j < 8; ++j)
#pragma unroll
      for (int t = 0; t < 3; ++t) wq[t][j] = dw[(h32 + d0q + j) * 3 + t];
#pragma unroll
    for (int ct = 0; ct < 2; ++ct) {
      const int row = w * 32 + ct * 16 + l15;
      const u16* src = base + (size_t)row * 768 + h32 + d0q;
      float v[8];
      const bfx8 bm = *(const bfx8*)src;
#pragma unroll
      for (int j = 0; j < 8; ++j) v[j] = wq[1][j] * bf2f((u16)bm[j]);
      if (row > 0) {
        const bfx8 bp = *(const bfx8*)(src - 768);
#pragma unroll
        for (int j = 0; j < 8; ++j) v[j] += wq[0][j] * bf2f((u16)bp[j]);
      }
      if (row < 255) {
        const bfx8 bn = *(const bfx8*)(src + 768);
#pragma unroll
        for (int j = 0; j < 8; ++j) v[j] += wq[2][j] * bf2f((u16)bn[j]);
      }
      float ssq = 0.f;
#pragma unroll
      for (int j = 0; j < 8; ++j) ssq += v[j] * v[j];
      ssq += __shfl_xor(ssq, 16);
      ssq += __shfl_xor(ssq, 32);
      const float inv = 1.f / fmaxf(sqrtf(ssq), 1e-12f);
      union { unsigned int u[4]; bfx8 b; } qb;
#pragma unroll
      for (int m = 0; m < 4; ++m) qb.u[m] = cvtpk(v[2 * m] * inv, v[2 * m + 1] * inv);
      bq[ct] = qb.b;
    }
  }

  // ---- staging roles: waves 0-3 stage K (row x 8ch), waves 4-7 stage V (ch x 8 keys) ----
  const bool isK = tid < 256;
  const int sV = tid & 255;
  const int krow = sV >> 2, kd0 = (sV & 3) * 8;  // K-stager coords
  const int vd = sV & 31, vko = sV >> 5;         // V-stager coords (d, key-octet)
  float wu[24];                                  // conv taps (K: 24, V: 3)
  if (isK) {
#pragma unroll
    for (int j = 0; j < 8; ++j)
#pragma unroll
      for (int t = 0; t < 3; ++t) wu[t * 8 + j] = dw[(256 + h32 + kd0 + j) * 3 + t];
  } else {
#pragma unroll
    for (int t = 0; t < 3; ++t) wu[t] = dw[(512 + h32 + vd) * 3 + t];
  }

  bfx8 km = {}, kp = {}, kn = {};
  u16 xs[10];

  auto stage_load = [&](int c) {
    if (isK) {
      const int gr = c * 64 + krow;
      const u16* src = base + (size_t)gr * 768 + 256 + h32 + kd0;
      km = *(const bfx8*)src;
      kp = (gr > 0) ? *(const bfx8*)(src - 768) : bfx8{};
      kn = (gr < 255) ? *(const bfx8*)(src + 768) : bfx8{};
    } else {
      const int g0 = c * 64 + vko * 8;
      const u16* src = base + (size_t)g0 * 768 + 512 + h32 + vd;
#pragma unroll
      for (int k = 0; k < 10; ++k) {
        const int gr = g0 + k - 1;
        xs[k] = (gr >= 0 && gr < 256) ? src[(ptrdiff_t)(k - 1) * 768] : (u16)0;
      }
    }
  };
  auto stage_finish = [&](int b) {
    if (isK) {
      float v[8];
#pragma unroll
      for (int j = 0; j < 8; ++j)
        v[j] = wu[8 + j] * bf2f((u16)km[j]) + wu[j] * bf2f((u16)kp[j]) +
               wu[16 + j] * bf2f((u16)kn[j]);
      float ssq = 0.f;
#pragma unroll
      for (int j = 0; j < 8; ++j) ssq += v[j] * v[j];
      ssq += __shfl_xor(ssq, 1);
      ssq += __shfl_xor(ssq, 2);
      const float inv = 1.f / fmaxf(sqrtf(ssq), 1e-12f);
      union { unsigned int u[4]; bfx8 b; } kb;
#pragma unroll
      for (int m = 0; m < 4; ++m) kb.u[m] = cvtpk(v[2 * m] * inv, v[2 * m + 1] * inv);
      *(bfx8*)&Kc[b][krow * 40 + kd0] = kb.b;
    } else {
      float x[10];
#pragma unroll
      for (int k = 0; k < 10; ++k) x[k] = bf2f(xs[k]);
      union { unsigned int u[4]; bfx8 b; } ob;
#pragma unroll
      for (int m = 0; m < 4; ++m) {
        float a0 = wu[0] * x[2 * m] + wu[1] * x[2 * m + 1] + wu[2] * x[2 * m + 2];
        float a1 = wu[0] * x[2 * m + 1] + wu[1] * x[2 * m + 2] + wu[2] * x[2 * m + 3];
        ob.u[m] = cvtpk(a0, a1);
      }
      const int po = vko ^ ((vd >> 3) & 3);  // octet swizzle: conflict-free wr/rd
      *(bfx8*)&Vt[b][vd * 72 + po * 8] = ob.b;
    }
  };

  f32x4 acc[2][2] = {};
  float lsum[2] = {0.f, 0.f};
  const f32x4 zf = {0.f, 0.f, 0.f, 0.f};
  const int fo = (l15 >> 3) & 1;

  stage_load(0);
  stage_finish(0);
  __syncthreads();

  for (int c = 0; c < 4; ++c) {
    const int b = c & 1;
    if (c < 3) stage_load(c + 1);

    bfx8 af[4];
#pragma unroll
    for (int rt = 0; rt < 4; ++rt)
      af[rt] = *(const bfx8*)&Kc[b][(rt * 16 + l15) * 40 + quad * 8];
#pragma unroll
    for (int ct = 0; ct < 2; ++ct) {
      unsigned int pu[4], pv[4];
#pragma unroll
      for (int rt = 0; rt < 4; ++rt) {
        f32x4 sc = __builtin_amdgcn_mfma_f32_16x16x32_bf16(af[rt], bq[ct], zf, 0, 0, 0);
        float e0 = exp2f(sc[0] * th2), e1 = exp2f(sc[1] * th2);
        float e2 = exp2f(sc[2] * th2), e3 = exp2f(sc[3] * th2);
        lsum[ct] += (e0 + e1) + (e2 + e3);
        pu[rt] = cvtpk(e0, e1);
        pv[rt] = cvtpk(e2, e3);
      }
#pragma unroll
      for (int ks = 0; ks < 2; ++ks) {
        // cross-quad relayout: score frag (4 keys @ quad*4) -> PV A-frag (8 keys @ quad*8)
        auto su = __builtin_amdgcn_permlane32_swap(pu[2 * ks], pu[2 * ks + 1], false, false);
        auto tu = __builtin_amdgcn_permlane16_swap(su[0], su[1], false, false);
        auto sv = __builtin_amdgcn_permlane32_swap(pv[2 * ks], pv[2 * ks + 1], false, false);
        auto tv = __builtin_amdgcn_permlane16_swap(sv[0], sv[1], false, false);
        union { unsigned int u[4]; bfx8 b; } ap;
        ap.u[0] = tu[0]; ap.u[1] = tv[0]; ap.u[2] = tu[1]; ap.u[3] = tv[1];
        const bfx8 bv0 = *(const bfx8*)&Vt[b][l15 * 72 + (ks * 4 + (quad ^ fo)) * 8];
        const bfx8 bv1 = *(const bfx8*)&Vt[b][(16 + l15) * 72 + (ks * 4 + (quad ^ (2 | fo))) * 8];
        acc[ct][0] = __builtin_amdgcn_mfma_f32_16x16x32_bf16(ap.b, bv0, acc[ct][0], 0, 0, 0);
        acc[ct][1] = __builtin_amdgcn_mfma_f32_16x16x32_bf16(ap.b, bv1, acc[ct][1], 0, 0, 0);
      }
    }
    if (c < 3) stage_finish(b ^ 1);
    __syncthreads();
  }

  // ---- softmax denominators: reduce across quads (wave-local, no barrier needed) ----
#pragma unroll
  for (int ct = 0; ct < 2; ++ct) {
    float L = lsum[ct];
    L += __shfl_xor(L, 16);
    L += __shfl_xor(L, 32);
    if (quad == 0) l_s[w * 32 + ct * 16 + l15] = L;
  }
  // same-wave write->read; compiler inserts the lgkmcnt wait
#pragma unroll
  for (int ct = 0; ct < 2; ++ct) {
    const f32x4 l4 = *(const f32x4*)&l_s[w * 32 + ct * 16 + quad * 4];
    float rinv[4];
#pragma unroll
    for (int r = 0; r < 4; ++r) rinv[r] = 1.f / l4[r];
#pragma unroll
    for (int dh = 0; dh < 2; ++dh)
#pragma unroll
      for (int r = 0; r < 4; ++r) {
        const int qrow = w * 32 + ct * 16 + quad * 4 + r;
        attn_out[((size_t)n * 256 + qrow) * 256 + h32 + dh * 16 + l15] =
            f2bf(acc[ct][dh][r] * rinv[r]);
      }
  }
}

// ---------------- LN2: wave per row, bf16 in/out ----------------
__launch_bounds__(256)
__global__ void ln2_kernel(const u16* __restrict__ in, const float* __restrict__ g,
                           const float* __restrict__ bta, u16* __restrict__ out) {
  const int lane = threadIdx.x & 63;
  const size_t row = (size_t)blockIdx.x * 4 + (threadIdx.x >> 6);
  const ushort4 u = ((const ushort4*)(in + row * 256))[lane];
  const float vx = bf2f(u.x), vy = bf2f(u.y), vz = bf2f(u.z), vw = bf2f(u.w);
  float s = vx + vy + vz + vw;
  float s2 = vx * vx + vy * vy + vz * vz + vw * vw;
#pragma unroll
  for (int m = 32; m >= 1; m >>= 1) {
    s += __shfl_xor(s, m, 64);
    s2 += __shfl_xor(s2, m, 64);
  }
  const float mu = s * (1.f / 256.f);
  const float rs = rsqrtf(s2 * (1.f / 256.f) - mu * mu + 1e-5f);
  const float4 gv = ((const float4*)g)[lane];
  const float4 bv = ((const float4*)bta)[lane];
  ushort4 o;
  o.x = f2bf((vx - mu) * rs * gv.x + bv.x);
  o.y = f2bf((vy - mu) * rs * gv.y + bv.y);
  o.z = f2bf((vz - mu) * rs * gv.z + bv.z);
  o.w = f2bf((vw - mu) * rs * gv.w + bv.w);
  ((ushort4*)(out + row * 256))[lane] = o;
}

extern "C" void kernel_launch(void* const* d_in, const int* in_sizes, int n_in,
                              void* d_out, int out_size, void* d_ws, size_t ws_size,
                              hipStream_t stream) {
  const float* x     = (const float*)d_in[0];
  const float* n1g   = (const float*)d_in[1];
  const float* n1b   = (const float*)d_in[2];
  const float* Wqkv  = (const float*)d_in[3];
  const float* dw    = (const float*)d_in[4];
  const float* Wproj = (const float*)d_in[5];
  const float* temp  = (const float*)d_in[6];
  const float* n2g   = (const float*)d_in[7];
  const float* n2b   = (const float*)d_in[8];
  const float* W1    = (const float*)d_in[9];
  const float* b1    = (const float*)d_in[10];
  const float* W2    = (const float*)d_in[11];
  const float* b2    = (const float*)d_in[12];

  // workspace (bf16 intermediates, peak 128 MiB):
  //   [0,  32M): xn -> attn_out -> xn2 -> (after MLP1) W2t stash
  //   [32M,128M): qkv;  after attn: out1 at [32M,64M), h1 at [64M,128M)
  char* ws = (char*)d_ws;
  u16* xn       = (u16*)(ws);
  u16* qkv      = (u16*)(ws + (32ull << 20));
  u16* attn_out = xn;
  u16* out1     = (u16*)(ws + (32ull << 20));
  u16* xn2      = xn;
  u16* h1       = (u16*)(ws + (64ull << 20));
  u16* w2t      = xn;  // xn region is dead after MLP1 reads xn2

  // transposed-weight stash in d_out (fully overwritten by the final GEMM)
  char* ob = (char*)d_out;
  u16* wqkvt  = (u16*)(ob);                 // 384 KiB
  u16* wprojt = (u16*)(ob + (1ull << 20));  // 128 KiB
  u16* w1t    = (u16*)(ob + 1572864ull);    // 256 KiB (at 1.5 MiB)

  transpose_w<<<dim3(24, 8), 256, 0, stream>>>(Wqkv, wqkvt, 256, 768);
  transpose_w<<<dim3(8, 8), 256, 0, stream>>>(Wproj, wprojt, 256, 256);
  transpose_w<<<dim3(16, 8), 256, 0, stream>>>(W1, w1t, 256, 512);

  ln1_kernel<<<2048, 256, 0, stream>>>(x, n1g, n1b, xn);
  gemm_mfma<256, 768, 0><<<dim3(6, 512), 256, 0, stream>>>(xn, wqkvt, qkv, nullptr, nullptr);
  attn_kernel<<<2048, 512, 0, stream>>>(qkv, dw, temp, attn_out);
  gemm_mfma<256, 256, 1><<<dim3(2, 512), 256, 0, stream>>>(attn_out, wprojt, out1, x, nullptr);
  ln2_kernel<<<16384, 256, 0, stream>>>(out1, n2g, n2b, xn2);
  gemm_mfma<256, 512, 2><<<dim3(4, 512), 256, 0, stream>>>(xn2, W1 ? w1t : w1t, h1, b1, nullptr);
  transpose_w<<<dim3(8, 16), 256, 0, stream>>>(W2, w2t, 512, 256);
  gemm_mfma<512, 256, 3><<<dim3(2, 512), 256, 0, stream>>>(h1, w2t, d_out, b2, out1);
}

// Round 8
// 395.434 us; speedup vs baseline: 1.3134x; 1.0035x over previous
//
#include <hip/hip_runtime.h>
#include <math.h>

// Dims (fixed by the problem)
#define Bv 4
#define Cv 256
#define Tv 64
#define Fv 256
#define Hv 8
#define HIDv 512
#define Mv 65536   // (B*T)*F rows
#define CTF (Cv * Tv * Fv)
#define TF (Tv * Fv)

typedef unsigned short u16;
typedef __attribute__((ext_vector_type(8))) short bfx8;
typedef __attribute__((ext_vector_type(4))) float f32x4;

__device__ __forceinline__ float bf2f(u16 u) {
  return __uint_as_float(((unsigned int)u) << 16);
}
__device__ __forceinline__ u16 f2bf(float f) {
  unsigned int x = __float_as_uint(f);
  unsigned int r = x + 0x7fffu + ((x >> 16) & 1u);
  return (u16)(r >> 16);
}
__device__ __forceinline__ unsigned int cvtpk(float a, float b) {
  unsigned int r;
  asm("v_cvt_pk_bf16_f32 %0, %1, %2" : "=v"(r) : "v"(a), "v"(b));
  return r;
}

// ---------------- one-shot weight transpose: fp32 [K][N] -> bf16 [N][K] ----------------
__launch_bounds__(256)
__global__ void transpose_w(const float* __restrict__ in, u16* __restrict__ out,
                            int K, int N) {
  __shared__ float t[32][33];
  const int n0 = blockIdx.x * 32, k0 = blockIdx.y * 32;
  const int c = threadIdx.x & 31, r = threadIdx.x >> 5;  // 32 cols x 8 rows
#pragma unroll
  for (int i = 0; i < 4; ++i)
    t[r + 8 * i][c] = in[(size_t)(k0 + r + 8 * i) * N + n0 + c];
  __syncthreads();
#pragma unroll
  for (int i = 0; i < 4; ++i)
    out[(size_t)(n0 + r + 8 * i) * K + k0 + c] = f2bf(t[c][r + 8 * i]);
}

// ---------------- LN1 fused with (B,C,T,F) -> (M, C) transpose; bf16 out ----------------
__launch_bounds__(256)
__global__ void ln1_kernel(const float* __restrict__ x, const float* __restrict__ g,
                           const float* __restrict__ bta, u16* __restrict__ xn) {
  __shared__ float tile[256][33];
  __shared__ float red1[8][32];
  __shared__ float red2[8][32];
  __shared__ float mu_s[32];
  __shared__ float rs_s[32];
  const int tid = threadIdx.x;
  const int blk = blockIdx.x;
  const int n = blk >> 3;           // 0..255 sequence index
  const int f0 = (blk & 7) << 5;    // 0,32,...,224
  const int bb = n >> 6, tt = n & 63;
  const float* xb = x + (size_t)bb * CTF + (size_t)tt * Fv;
  const int fl = tid & 31, c0 = tid >> 5;
#pragma unroll
  for (int i = 0; i < 32; ++i) {
    int c = i * 8 + c0;
    tile[c][fl] = xb[(size_t)c * TF + f0 + fl];
  }
  __syncthreads();
  const int col = tid & 31, part = tid >> 5;
  float s = 0.f, s2 = 0.f;
#pragma unroll
  for (int i = 0; i < 32; ++i) {
    float v = tile[part * 32 + i][col];
    s += v; s2 += v * v;
  }
  red1[part][col] = s; red2[part][col] = s2;
  __syncthreads();
  if (tid < 32) {
    float S1 = 0.f, S2 = 0.f;
#pragma unroll
    for (int p = 0; p < 8; ++p) { S1 += red1[p][tid]; S2 += red2[p][tid]; }
    float m = S1 * (1.f / 256.f);
    float var = S2 * (1.f / 256.f) - m * m;
    mu_s[tid] = m;
    rs_s[tid] = rsqrtf(var + 1e-5f);
  }
  __syncthreads();
  const float gv = g[tid], bv = bta[tid];
  u16* ob = xn + ((size_t)n * 256 + f0) * 256 + tid;
#pragma unroll
  for (int fl2 = 0; fl2 < 32; ++fl2) {
    ob[(size_t)fl2 * 256] = f2bf((tile[tid][fl2] - mu_s[fl2]) * rs_s[fl2] * gv + bv);
  }
}

// ---------------- MFMA GEMM: C[M,N] = A[M,K](bf16) @ Bt[N,K](bf16)^T + epilogue ----------
// Round-8: staging via global_load_lds width=16 (m97 ladder step 3), linear LDS
// [128][64] with T21 both-sides XOR swizzle: source column chunk (l&7)^(l>>3),
// read chunk (s*4+quad)^(row&7). No ds_writes, LDS 45->32 KiB (5 blocks/CU).
template <int K, int N, int EPI>
__launch_bounds__(256)
__global__ void gemm_mfma(const u16* __restrict__ A, const u16* __restrict__ Bt,
                          void* __restrict__ Cc, const float* __restrict__ aux0,
                          const u16* __restrict__ aux1) {
  constexpr int GX = N / 128;
  __shared__ u16 As[128 * 64];
  __shared__ u16 Bs[128 * 64];
  const int tid = threadIdx.x;
  const int lane = tid & 63, wid = tid >> 6;
  // XCD-aware bijective chunk swizzle (grid.x*grid.y % 8 == 0 for all launches)
  int id = blockIdx.y * GX + blockIdx.x;
  const int qch = (GX * gridDim.y) >> 3;
  id = (id & 7) * qch + (id >> 3);
  const int m0 = (id / GX) * 128, n0 = (id % GX) * 128;
  const int wm = (wid & 1) * 64, wn = (wid >> 1) * 64;
  const int lm = lane & 15, quad = lane >> 4;

  const int l8 = lane >> 3, c8 = lane & 7;
  const int gc = (c8 ^ l8) * 8;  // inverse-swizzled source column (elements)

  f32x4 acc[4][4] = {};
  for (int k0 = 0; k0 < K; k0 += 64) {
    __syncthreads();  // previous compute done reading LDS (no-op on first iter)
#pragma unroll
    for (int i = 0; i < 4; ++i) {
      const int rb = wid * 32 + i * 8;   // wave-uniform LDS base row
      const int row = rb + l8;
      __builtin_amdgcn_global_load_lds(
          (const __attribute__((address_space(1))) void*)(A + (size_t)(m0 + row) * K + k0 + gc),
          (__attribute__((address_space(3))) void*)(&As[rb * 64]), 16, 0, 0);
      __builtin_amdgcn_global_load_lds(
          (const __attribute__((address_space(1))) void*)(Bt + (size_t)(n0 + row) * K + k0 + gc),
          (__attribute__((address_space(3))) void*)(&Bs[rb * 64]), 16, 0, 0);
    }
    __syncthreads();  // drains vmcnt -> staged tile visible
#pragma unroll
    for (int s = 0; s < 2; ++s) {
      bfx8 af[4], bf[4];
#pragma unroll
      for (int t = 0; t < 4; ++t) {
        const int ra = wm + t * 16 + lm;
        const int rbr = wn + t * 16 + lm;
        af[t] = *(const bfx8*)&As[ra * 64 + (((s * 4 + quad) ^ (ra & 7))) * 8];
        bf[t] = *(const bfx8*)&Bs[rbr * 64 + (((s * 4 + quad) ^ (rbr & 7))) * 8];
      }
#pragma unroll
      for (int tm = 0; tm < 4; ++tm)
#pragma unroll
        for (int tn = 0; tn < 4; ++tn)
          acc[tm][tn] = __builtin_amdgcn_mfma_f32_16x16x32_bf16(af[tm], bf[tn], acc[tm][tn], 0, 0, 0);
    }
  }

  const int row_l = quad * 4;
  const int nn = m0 >> 8;
  const int bb = nn >> 6, tt = nn & 63;
  const int srow_base = (m0 & 255) + wm;
  float bcol[4];
  if constexpr (EPI == 2 || EPI == 3) {
#pragma unroll
    for (int tn = 0; tn < 4; ++tn) bcol[tn] = aux0[n0 + wn + tn * 16 + lm];
  }
#pragma unroll
  for (int tm = 0; tm < 4; ++tm) {
    const int grow0 = m0 + wm + tm * 16 + row_l;
    const int sr0 = srow_base + tm * 16 + row_l;
#pragma unroll
    for (int tn = 0; tn < 4; ++tn) {
      const int gcol = n0 + wn + tn * 16 + lm;
      if constexpr (EPI == 0) {
#pragma unroll
        for (int r = 0; r < 4; ++r)
          ((u16*)Cc)[(size_t)(grow0 + r) * N + gcol] = f2bf(acc[tm][tn][r]);
      } else if constexpr (EPI == 1) {
        const float4 xv = *(const float4*)(aux0 + (size_t)bb * CTF + (size_t)gcol * TF + tt * Fv + sr0);
        const float xr[4] = {xv.x, xv.y, xv.z, xv.w};
#pragma unroll
        for (int r = 0; r < 4; ++r)
          ((u16*)Cc)[(size_t)(grow0 + r) * N + gcol] = f2bf(acc[tm][tn][r] + xr[r]);
      } else if constexpr (EPI == 2) {
#pragma unroll
        for (int r = 0; r < 4; ++r) {
          float v = acc[tm][tn][r] + bcol[tn];
          float y = 0.79788456080286536f * (v + 0.044715f * v * v * v);
          float th = 1.f - 2.f / (__expf(2.f * y) + 1.f);
          ((u16*)Cc)[(size_t)(grow0 + r) * N + gcol] = f2bf(0.5f * v * (1.f + th));
        }
      } else {  // EPI 3
        float4 o;
#pragma unroll
        for (int r = 0; r < 4; ++r) {
          float res = bf2f(aux1[(size_t)(grow0 + r) * 256 + gcol]);
          ((float*)&o)[r] = acc[tm][tn][r] + bcol[tn] + res;
        }
        *(float4*)((float*)Cc + (size_t)bb * CTF + (size_t)gcol * TF + tt * Fv + sr0) = o;
      }
    }
  }
}

// ---------------- MFMA flash attention: one block per (n,h), 8 waves ----------------
// Verified structure (round 6: 100.7 us, no spill at VGPR=108).
__launch_bounds__(512)
__global__ void attn_kernel(const u16* __restrict__ qkv, const float* __restrict__ dw,
                            const float* __restrict__ temp, u16* __restrict__ attn_out) {
  __shared__ u16 Kc[2][64 * 40];   // [key][ch] stride 40 u16 (80 B) — 5120 B each
  __shared__ u16 Vt[2][32 * 72];   // [d][key], key-octet XOR-swizzled — 4608 B each
  __shared__ float l_s[256];       // per-qrow softmax denominators
  const int tid = threadIdx.x;
  const int lane = tid & 63, w = tid >> 6;       // 8 waves, 32 qrows each
  const int l15 = lane & 15, quad = lane >> 4;
  const int n = blockIdx.x >> 3, h = blockIdx.x & 7;
  const int h32 = h * 32;
  const u16* base = qkv + (size_t)n * 256 * 768;
  const float th2 = temp[h] * 1.44269504089f;    // fold log2(e) into temperature

  // ---- Q: conv3 + l2norm directly into per-thread B-frags (qrow = w*32+ct*16+l15) ----
  bfx8 bq[2];
  {
    const int d0q = quad * 8;
    float wq[3][8];
#pragma unroll
    for (int j = 0; j < 8; ++j)
#pragma unroll
      for (int t = 0; t < 3; ++t) wq[t][j] = dw[(h32 + d0q + j) * 3 + t];
#pragma unroll
    for (int ct = 0; ct < 2; ++ct) {
      const int row = w * 32 + ct * 16 + l15;
      const u16* src = base + (size_t)row * 768 + h32 + d0q;
      float v[8];
      const bfx8 bm = *(const bfx8*)src;
#pragma unroll
      for (int j = 0; j < 8; ++j) v[j] = wq[1][j] * bf2f((u16)bm[j]);
      if (row > 0) {
        const bfx8 bp = *(const bfx8*)(src - 768);
#pragma unroll
        for (int j = 0; j < 8; ++j) v[j] += wq[0][j] * bf2f((u16)bp[j]);
      }
      if (row < 255) {
        const bfx8 bn = *(const bfx8*)(src + 768);
#pragma unroll
        for (int j = 0; j < 8; ++j) v[j] += wq[2][j] * bf2f((u16)bn[j]);
      }
      float ssq = 0.f;
#pragma unroll
      for (int j = 0; j < 8; ++j) ssq += v[j] * v[j];
      ssq += __shfl_xor(ssq, 16);
      ssq += __shfl_xor(ssq, 32);
      const float inv = 1.f / fmaxf(sqrtf(ssq), 1e-12f);
      union { unsigned int u[4]; bfx8 b; } qb;
#pragma unroll
      for (int m = 0; m < 4; ++m) qb.u[m] = cvtpk(v[2 * m] * inv, v[2 * m + 1] * inv);
      bq[ct] = qb.b;
    }
  }

  // ---- staging roles: waves 0-3 stage K (row x 8ch), waves 4-7 stage V (ch x 8 keys) ----
  const bool isK = tid < 256;
  const int sV = tid & 255;
  const int krow = sV >> 2, kd0 = (sV & 3) * 8;  // K-stager coords
  const int vd = sV & 31, vko = sV >> 5;         // V-stager coords (d, key-octet)
  float wu[24];                                  // conv taps (K: 24, V: 3)
  if (isK) {
#pragma unroll
    for (int j = 0; j < 8; ++j)
#pragma unroll
      for (int t = 0; t < 3; ++t) wu[t * 8 + j] = dw[(256 + h32 + kd0 + j) * 3 + t];
  } else {
#pragma unroll
    for (int t = 0; t < 3; ++t) wu[t] = dw[(512 + h32 + vd) * 3 + t];
  }

  bfx8 km = {}, kp = {}, kn = {};
  u16 xs[10];

  auto stage_load = [&](int c) {
    if (isK) {
      const int gr = c * 64 + krow;
      const u16* src = base + (size_t)gr * 768 + 256 + h32 + kd0;
      km = *(const bfx8*)src;
      kp = (gr > 0) ? *(const bfx8*)(src - 768) : bfx8{};
      kn = (gr < 255) ? *(const bfx8*)(src + 768) : bfx8{};
    } else {
      const int g0 = c * 64 + vko * 8;
      const u16* src = base + (size_t)g0 * 768 + 512 + h32 + vd;
#pragma unroll
      for (int k = 0; k < 10; ++k) {
        const int gr = g0 + k - 1;
        xs[k] = (gr >= 0 && gr < 256) ? src[(ptrdiff_t)(k - 1) * 768] : (u16)0;
      }
    }
  };
  auto stage_finish = [&](int b) {
    if (isK) {
      float v[8];
#pragma unroll
      for (int j = 0; j < 8; ++j)
        v[j] = wu[8 + j] * bf2f((u16)km[j]) + wu[j] * bf2f((u16)kp[j]) +
               wu[16 + j] * bf2f((u16)kn[j]);
      float ssq = 0.f;
#pragma unroll
      for (int j = 0; j < 8; ++j) ssq += v[j] * v[j];
      ssq += __shfl_xor(ssq, 1);
      ssq += __shfl_xor(ssq, 2);
      const float inv = 1.f / fmaxf(sqrtf(ssq), 1e-12f);
      union { unsigned int u[4]; bfx8 b; } kb;
#pragma unroll
      for (int m = 0; m < 4; ++m) kb.u[m] = cvtpk(v[2 * m] * inv, v[2 * m + 1] * inv);
      *(bfx8*)&Kc[b][krow * 40 + kd0] = kb.b;
    } else {
      float x[10];
#pragma unroll
      for (int k = 0; k < 10; ++k) x[k] = bf2f(xs[k]);
      union { unsigned int u[4]; bfx8 b; } ob;
#pragma unroll
      for (int m = 0; m < 4; ++m) {
        float a0 = wu[0] * x[2 * m] + wu[1] * x[2 * m + 1] + wu[2] * x[2 * m + 2];
        float a1 = wu[0] * x[2 * m + 1] + wu[1] * x[2 * m + 2] + wu[2] * x[2 * m + 3];
        ob.u[m] = cvtpk(a0, a1);
      }
      const int po = vko ^ ((vd >> 3) & 3);  // octet swizzle: conflict-free wr/rd
      *(bfx8*)&Vt[b][vd * 72 + po * 8] = ob.b;
    }
  };

  f32x4 acc[2][2] = {};
  float lsum[2] = {0.f, 0.f};
  const f32x4 zf = {0.f, 0.f, 0.f, 0.f};
  const int fo = (l15 >> 3) & 1;

  stage_load(0);
  stage_finish(0);
  __syncthreads();

  for (int c = 0; c < 4; ++c) {
    const int b = c & 1;
    if (c < 3) stage_load(c + 1);

    bfx8 af[4];
#pragma unroll
    for (int rt = 0; rt < 4; ++rt)
      af[rt] = *(const bfx8*)&Kc[b][(rt * 16 + l15) * 40 + quad * 8];
#pragma unroll
    for (int ct = 0; ct < 2; ++ct) {
      unsigned int pu[4], pv[4];
#pragma unroll
      for (int rt = 0; rt < 4; ++rt) {
        f32x4 sc = __builtin_amdgcn_mfma_f32_16x16x32_bf16(af[rt], bq[ct], zf, 0, 0, 0);
        float e0 = exp2f(sc[0] * th2), e1 = exp2f(sc[1] * th2);
        float e2 = exp2f(sc[2] * th2), e3 = exp2f(sc[3] * th2);
        lsum[ct] += (e0 + e1) + (e2 + e3);
        pu[rt] = cvtpk(e0, e1);
        pv[rt] = cvtpk(e2, e3);
      }
#pragma unroll
      for (int ks = 0; ks < 2; ++ks) {
        // cross-quad relayout: score frag (4 keys @ quad*4) -> PV A-frag (8 keys @ quad*8)
        auto su = __builtin_amdgcn_permlane32_swap(pu[2 * ks], pu[2 * ks + 1], false, false);
        auto tu = __builtin_amdgcn_permlane16_swap(su[0], su[1], false, false);
        auto sv = __builtin_amdgcn_permlane32_swap(pv[2 * ks], pv[2 * ks + 1], false, false);
        auto tv = __builtin_amdgcn_permlane16_swap(sv[0], sv[1], false, false);
        union { unsigned int u[4]; bfx8 b; } ap;
        ap.u[0] = tu[0]; ap.u[1] = tv[0]; ap.u[2] = tu[1]; ap.u[3] = tv[1];
        const bfx8 bv0 = *(const bfx8*)&Vt[b][l15 * 72 + (ks * 4 + (quad ^ fo)) * 8];
        const bfx8 bv1 = *(const bfx8*)&Vt[b][(16 + l15) * 72 + (ks * 4 + (quad ^ (2 | fo))) * 8];
        acc[ct][0] = __builtin_amdgcn_mfma_f32_16x16x32_bf16(ap.b, bv0, acc[ct][0], 0, 0, 0);
        acc[ct][1] = __builtin_amdgcn_mfma_f32_16x16x32_bf16(ap.b, bv1, acc[ct][1], 0, 0, 0);
      }
    }
    if (c < 3) stage_finish(b ^ 1);
    __syncthreads();
  }

  // ---- softmax denominators: reduce across quads (wave-local, no barrier needed) ----
#pragma unroll
  for (int ct = 0; ct < 2; ++ct) {
    float L = lsum[ct];
    L += __shfl_xor(L, 16);
    L += __shfl_xor(L, 32);
    if (quad == 0) l_s[w * 32 + ct * 16 + l15] = L;
  }
  // same-wave write->read; compiler inserts the lgkmcnt wait
#pragma unroll
  for (int ct = 0; ct < 2; ++ct) {
    const f32x4 l4 = *(const f32x4*)&l_s[w * 32 + ct * 16 + quad * 4];
    float rinv[4];
#pragma unroll
    for (int r = 0; r < 4; ++r) rinv[r] = 1.f / l4[r];
#pragma unroll
    for (int dh = 0; dh < 2; ++dh)
#pragma unroll
      for (int r = 0; r < 4; ++r) {
        const int qrow = w * 32 + ct * 16 + quad * 4 + r;
        attn_out[((size_t)n * 256 + qrow) * 256 + h32 + dh * 16 + l15] =
            f2bf(acc[ct][dh][r] * rinv[r]);
      }
  }
}

// ---------------- LN2: wave per row, bf16 in/out ----------------
__launch_bounds__(256)
__global__ void ln2_kernel(const u16* __restrict__ in, const float* __restrict__ g,
                           const float* __restrict__ bta, u16* __restrict__ out) {
  const int lane = threadIdx.x & 63;
  const size_t row = (size_t)blockIdx.x * 4 + (threadIdx.x >> 6);
  const ushort4 u = ((const ushort4*)(in + row * 256))[lane];
  const float vx = bf2f(u.x), vy = bf2f(u.y), vz = bf2f(u.z), vw = bf2f(u.w);
  float s = vx + vy + vz + vw;
  float s2 = vx * vx + vy * vy + vz * vz + vw * vw;
#pragma unroll
  for (int m = 32; m >= 1; m >>= 1) {
    s += __shfl_xor(s, m, 64);
    s2 += __shfl_xor(s2, m, 64);
  }
  const float mu = s * (1.f / 256.f);
  const float rs = rsqrtf(s2 * (1.f / 256.f) - mu * mu + 1e-5f);
  const float4 gv = ((const float4*)g)[lane];
  const float4 bv = ((const float4*)bta)[lane];
  ushort4 o;
  o.x = f2bf((vx - mu) * rs * gv.x + bv.x);
  o.y = f2bf((vy - mu) * rs * gv.y + bv.y);
  o.z = f2bf((vz - mu) * rs * gv.z + bv.z);
  o.w = f2bf((vw - mu) * rs * gv.w + bv.w);
  ((ushort4*)(out + row * 256))[lane] = o;
}

extern "C" void kernel_launch(void* const* d_in, const int* in_sizes, int n_in,
                              void* d_out, int out_size, void* d_ws, size_t ws_size,
                              hipStream_t stream) {
  const float* x     = (const float*)d_in[0];
  const float* n1g   = (const float*)d_in[1];
  const float* n1b   = (const float*)d_in[2];
  const float* Wqkv  = (const float*)d_in[3];
  const float* dw    = (const float*)d_in[4];
  const float* Wproj = (const float*)d_in[5];
  const float* temp  = (const float*)d_in[6];
  const float* n2g   = (const float*)d_in[7];
  const float* n2b   = (const float*)d_in[8];
  const float* W1    = (const float*)d_in[9];
  const float* b1    = (const float*)d_in[10];
  const float* W2    = (const float*)d_in[11];
  const float* b2    = (const float*)d_in[12];

  // workspace (bf16 intermediates, peak 128 MiB):
  //   [0,  32M): xn -> attn_out -> xn2 -> (after MLP1) W2t stash
  //   [32M,128M): qkv;  after attn: out1 at [32M,64M), h1 at [64M,128M)
  char* ws = (char*)d_ws;
  u16* xn       = (u16*)(ws);
  u16* qkv      = (u16*)(ws + (32ull << 20));
  u16* attn_out = xn;
  u16* out1     = (u16*)(ws + (32ull << 20));
  u16* xn2      = xn;
  u16* h1       = (u16*)(ws + (64ull << 20));
  u16* w2t      = xn;  // xn region is dead after MLP1 reads xn2

  // transposed-weight stash in d_out (fully overwritten by the final GEMM)
  char* ob = (char*)d_out;
  u16* wqkvt  = (u16*)(ob);                 // 384 KiB
  u16* wprojt = (u16*)(ob + (1ull << 20));  // 128 KiB
  u16* w1t    = (u16*)(ob + 1572864ull);    // 256 KiB (at 1.5 MiB)

  transpose_w<<<dim3(24, 8), 256, 0, stream>>>(Wqkv, wqkvt, 256, 768);
  transpose_w<<<dim3(8, 8), 256, 0, stream>>>(Wproj, wprojt, 256, 256);
  transpose_w<<<dim3(16, 8), 256, 0, stream>>>(W1, w1t, 256, 512);

  ln1_kernel<<<2048, 256, 0, stream>>>(x, n1g, n1b, xn);
  gemm_mfma<256, 768, 0><<<dim3(6, 512), 256, 0, stream>>>(xn, wqkvt, qkv, nullptr, nullptr);
  attn_kernel<<<2048, 512, 0, stream>>>(qkv, dw, temp, attn_out);
  gemm_mfma<256, 256, 1><<<dim3(2, 512), 256, 0, stream>>>(attn_out, wprojt, out1, x, nullptr);
  ln2_kernel<<<16384, 256, 0, stream>>>(out1, n2g, n2b, xn2);
  gemm_mfma<256, 512, 2><<<dim3(4, 512), 256, 0, stream>>>(xn2, W1 ? w1t : w1t, h1, b1, nullptr);
  transpose_w<<<dim3(8, 16), 256, 0, stream>>>(W2, w2t, 512, 256);
  gemm_mfma<512, 256, 3><<<dim3(2, 512), 256, 0, stream>>>(h1, w2t, d_out, b2, out1);
}